// Round 6
// baseline (3297.886 us; speedup 1.0000x reference)
//
#include <hip/hip_runtime.h>
#include <hip/hip_bf16.h>

// EncoderGRUODE on MI355X — round 6 (re-run of round-5 design; R5 never ran:
// GPU acquisition timeout).
// R1-R3: three staging schemes, bytes 640->384 KB/step, time ~constant 10.5-11.7
// µs/step -> per-chunk wait ~1500-2000 cy with only depth-2/3 lookahead. R4's
// TLP attempt crashed on VGPR/block-size overcommit. This round: proven R3
// geometry (32 blk x 512 thr, 8 waves x 32 cols) + DEEP register pipeline:
// no resident weights (frees 128 VGPRs); w1/w2/whh/x stream as a 21-position
// cycle through 7 rotating int4[4] landing buffers (consume p -> reissue p+7
// into the same buffer). 21 = 3*7 so the static map repeats every step, and
// t-invariant weights let the cycle wrap across steps: ~28 loads permanently
// in flight, riding across the lgkm-only barriers. Branchless t=0 keeps the
// schedule uniform. Compiler-managed waitcnt (per-register) — spill-safe.

#define Bn 512
#define Tn 256
#define Dn 64
#define Hn 256

typedef __bf16 bf16x8 __attribute__((ext_vector_type(8)));
typedef float f32x4 __attribute__((ext_vector_type(4)));

__device__ __forceinline__ f32x4 mfma_bf16(bf16x8 a, bf16x8 b, f32x4 c) {
  return __builtin_amdgcn_mfma_f32_16x16x32_bf16(a, b, c, 0, 0, 0);
}
__device__ __forceinline__ float fast_sigmoid(float x) {
  return __builtin_amdgcn_rcpf(1.0f + __expf(-x));
}
__device__ __forceinline__ float fast_tanh(float x) {
  return 1.0f - 2.0f * __builtin_amdgcn_rcpf(1.0f + __expf(2.0f * x));
}
__device__ __forceinline__ bf16x8 as_bf16x8(int4 v) { return __builtin_bit_cast(bf16x8, v); }
__device__ __forceinline__ f32x4 as_f32x4(int4 v) { return __builtin_bit_cast(f32x4, v); }

// Pack [N][K] fp32 row-major -> bf16 MFMA-B-fragment order:
// element (n,k) -> [((n/16)*(K/32) + k/32)*64 + (n%16) + 16*((k%32)/8)]*8 + k%8
__global__ void pack_w(const float* __restrict__ w, __bf16* __restrict__ out,
                       int N, int K) {
  int idx = blockIdx.x * blockDim.x + threadIdx.x;
  if (idx >= N * K) return;
  int n = idx / K, k = idx % K;
  int tile = n >> 4, kb = k >> 5;
  int lane = (n & 15) + (((k & 31) >> 3) << 4);
  int j = k & 7;
  out[(((tile * (K >> 5) + kb) << 6) + lane) * 8 + j] = (__bf16)w[idx];
}

__global__ void pack_w_hilo(const float* __restrict__ w, __bf16* __restrict__ hi,
                            __bf16* __restrict__ lo, int N, int K) {
  int idx = blockIdx.x * blockDim.x + threadIdx.x;
  if (idx >= N * K) return;
  int n = idx / K, k = idx % K;
  int tile = n >> 4, kb = k >> 5;
  int lane = (n & 15) + (((k & 31) >> 3) << 4);
  int j = k & 7;
  int o = (((tile * (K >> 5) + kb) << 6) + lane) * 8 + j;
  float f = w[idx];
  __bf16 h = (__bf16)f;
  hi[o] = h;
  lo[o] = (__bf16)(f - (float)h);
}

#define BAR()                                        \
  asm volatile("s_waitcnt lgkmcnt(0)" ::: "memory"); \
  __builtin_amdgcn_sched_barrier(0);                 \
  __builtin_amdgcn_s_barrier();                      \
  __builtin_amdgcn_sched_barrier(0);

// --- stream issue macros (B = buffer index 0..6, static at each call site) ---
// w1/w2 chunk i (0..3): tile = 2wv + (i>>1), kb0 = (i&1)*4
#define LD_W1(B, i)                                                        \
  { _Pragma("unroll") for (int f_ = 0; f_ < 4; f_++)                       \
      wb[B][f_] = w1i[((2 * wv + ((i) >> 1)) * 8 + ((i) & 1) * 4 + f_) * 64 + l]; }
#define LD_W2(B, i)                                                        \
  { _Pragma("unroll") for (int f_ = 0; f_ < 4; f_++)                       \
      wb[B][f_] = w2i[((2 * wv + ((i) >> 1)) * 8 + ((i) & 1) * 4 + f_) * 64 + l]; }
// whh chunk j (0..11): q=j%6 -> gate=q>>1, nt=q&1; kb0=(j/6)*4
#define LD_WH(B, j)                                                        \
  { const int tl_ = (((j) % 6) >> 1) * 16 + 2 * wv + (((j) % 6) & 1);      \
    const int k0_ = ((j) / 6) * 4;                                         \
    _Pragma("unroll") for (int f_ = 0; f_ < 4; f_++)                       \
        wb[B][f_] = whi[(tl_ * 8 + k0_ + f_) * 64 + l]; }
// x for step tt (clamped): 4x16B per-lane loads in A-fragment order
#define LD_X(B, tt)                                                        \
  { const float* xs_ = xrow + (((tt) < Tn) ? (tt) : Tn - 1) * Dn;          \
    wb[B][0] = *(const int4*)(xs_);                                        \
    wb[B][1] = *(const int4*)(xs_ + 4);                                    \
    wb[B][2] = *(const int4*)(xs_ + 32);                                   \
    wb[B][3] = *(const int4*)(xs_ + 36); }

__launch_bounds__(512, 2)
__global__ void gru_ode_kernel(
    const float* __restrict__ x, const float* __restrict__ tps,
    const float* __restrict__ mask,
    const float* __restrict__ b_ih, const float* __restrict__ b_hh,
    const float* __restrict__ b1, const float* __restrict__ b2,
    const float* __restrict__ b_out,
    const __bf16* __restrict__ w1p, const __bf16* __restrict__ w2p,
    const __bf16* __restrict__ whhp, const __bf16* __restrict__ wihp,
    const __bf16* __restrict__ wouth, const __bf16* __restrict__ woutl,
    float* __restrict__ out) {
  __shared__ __align__(16) __bf16 wih_l[49152];  // w_ih packed, 96KB, resident
  __shared__ __align__(16) __bf16 h_fr[4096];    // h_new fragments [kb8][lane64][8]
  __shared__ __align__(16) __bf16 a_fr[4096];    // tanh() fragments
  __shared__ __align__(16) __bf16 o_fr[4096];    // h_ode fragments
  __shared__ __align__(16) float hlast[16][260];
  __shared__ float dt_s[Tn];
  __shared__ int len_s[16];
  __shared__ int maxlen_s;

  const int tid = threadIdx.x;
  const int wv = tid >> 6;  // wave 0..7: owns cols [32*wv, 32*wv+32)
  const int l = tid & 63;
  const int g = l >> 4;   // lane k-group
  const int c = l & 15;   // lane row/col-in-tile
  const int m0 = blockIdx.x << 4;

  if (tid < Tn) dt_s[tid] = tid ? tps[tid] - tps[tid - 1] : 0.0f;  // dt[0]=0: branchless t=0
#pragma unroll
  for (int i = 0; i < 8; i++) {
    h_fr[tid + i * 512] = (__bf16)0.0f;
    o_fr[tid + i * 512] = (__bf16)0.0f;
  }
  {
    const int4* s4 = (const int4*)wihp;
    int4* d4 = (int4*)wih_l;
    for (int i = tid; i < 6144; i += 512) d4[i] = s4[i];
  }
  {
    int m = tid >> 5, l32 = tid & 31;
    const float* mr = mask + (size_t)(m0 + m) * Tn + l32 * 8;
    float s = 0.f;
#pragma unroll
    for (int i = 0; i < 8; i++) s += mr[i];
#pragma unroll
    for (int o = 16; o; o >>= 1) s += __shfl_down(s, o, 32);
    if (l32 == 0) len_s[m] = (int)(s + 0.5f);
  }
  __syncthreads();
  if (tid == 0) {
    int mx = 1;
    for (int i = 0; i < 16; i++) mx = max(mx, len_s[i]);
    maxlen_s = mx;
  }
  __syncthreads();
  const int maxlen = maxlen_s;
  int len4[4];
#pragma unroll
  for (int r = 0; r < 4; r++) len4[r] = len_s[4 * g + r];

  float bb1[2], bb2[2], brz[4], bin[2], bhn[2], bo[2];
#pragma unroll
  for (int nt = 0; nt < 2; nt++) {
    int col = 32 * wv + 16 * nt + c;
    bb1[nt] = b1[col];
    bb2[nt] = b2[col];
    brz[nt] = b_ih[col] + b_hh[col];
    brz[2 + nt] = b_ih[256 + col] + b_hh[256 + col];
    bin[nt] = b_ih[512 + col];
    bhn[nt] = b_hh[512 + col];
    bo[nt] = b_out[col];
  }

  float hreg[2][4] = {{0, 0, 0, 0}, {0, 0, 0, 0}};  // fp32 master h slice

  const int4* w1i = (const int4*)w1p;
  const int4* w2i = (const int4*)w2p;
  const int4* whi = (const int4*)whhp;
  const bf16x8* wifl = (const bf16x8*)wih_l;
  const float* xrow = x + (size_t)(m0 + c) * (Tn * Dn) + 8 * g;

  // scatter-write base: (wv*64 + 4g + 32nt + 16*(c>>3) + r)*8 + (c&7)
  const int wbase = (wv * 64 + 4 * g + 16 * (c >> 3)) * 8 + (c & 7);

  // ---- 7 rotating landing buffers; prologue = positions 0..6 of step 0.
  int4 wb[7][4];
  LD_X(0, 0);
  LD_W1(1, 0);
  LD_W1(2, 1);
  LD_W1(3, 2);
  LD_W1(4, 3);
  LD_W2(5, 0);
  LD_W2(6, 1);

  for (int t = 0; t < maxlen; t++) {
    // ---- pos 0: consume X(t) -> xf0/xf1 ; issue B2
    bf16x8 xf0, xf1;
    {
      f32x4 a0 = as_f32x4(wb[0][0]), a1 = as_f32x4(wb[0][1]);
      f32x4 a2 = as_f32x4(wb[0][2]), a3 = as_f32x4(wb[0][3]);
#pragma unroll
      for (int j = 0; j < 4; j++) {
        xf0[j] = (__bf16)a0[j]; xf0[4 + j] = (__bf16)a1[j];
        xf1[j] = (__bf16)a2[j]; xf1[4 + j] = (__bf16)a3[j];
      }
    }
    LD_W2(0, 2);

    // ---- Phase A: a = tanh(h @ w1^T + b1); consume A0..A3 (bufs 1-4)
    {
      bf16x8 hv[8];
#pragma unroll
      for (int kb = 0; kb < 8; kb++) hv[kb] = *(const bf16x8*)&h_fr[(kb * 64 + l) * 8];
      f32x4 accA0 = {0.f, 0.f, 0.f, 0.f}, accA1 = {0.f, 0.f, 0.f, 0.f};
#pragma unroll
      for (int f = 0; f < 4; f++) accA0 = mfma_bf16(hv[f], as_bf16x8(wb[1][f]), accA0);
      LD_W2(1, 3);
#pragma unroll
      for (int f = 0; f < 4; f++) accA0 = mfma_bf16(hv[4 + f], as_bf16x8(wb[2][f]), accA0);
      LD_WH(2, 0);
#pragma unroll
      for (int f = 0; f < 4; f++) accA1 = mfma_bf16(hv[f], as_bf16x8(wb[3][f]), accA1);
      LD_WH(3, 1);
#pragma unroll
      for (int f = 0; f < 4; f++) accA1 = mfma_bf16(hv[4 + f], as_bf16x8(wb[4][f]), accA1);
      LD_WH(4, 2);
#pragma unroll
      for (int r = 0; r < 4; r++) {
        a_fr[wbase + r * 8] = (__bf16)fast_tanh(accA0[r] + bb1[0]);
        a_fr[wbase + (r + 32) * 8] = (__bf16)fast_tanh(accA1[r] + bb1[1]);
      }
    }
    BAR();

    // ---- Phase B: h_ode = h + dt*(a @ w2^T + b2); consume B0..B3 (bufs 5,6,0,1)
    {
      bf16x8 av[8];
#pragma unroll
      for (int kb = 0; kb < 8; kb++) av[kb] = *(const bf16x8*)&a_fr[(kb * 64 + l) * 8];
      f32x4 accB0 = {0.f, 0.f, 0.f, 0.f}, accB1 = {0.f, 0.f, 0.f, 0.f};
#pragma unroll
      for (int f = 0; f < 4; f++) accB0 = mfma_bf16(av[f], as_bf16x8(wb[5][f]), accB0);
      LD_WH(5, 3);
#pragma unroll
      for (int f = 0; f < 4; f++) accB0 = mfma_bf16(av[4 + f], as_bf16x8(wb[6][f]), accB0);
      LD_WH(6, 4);
#pragma unroll
      for (int f = 0; f < 4; f++) accB1 = mfma_bf16(av[f], as_bf16x8(wb[0][f]), accB1);
      LD_WH(0, 5);
#pragma unroll
      for (int f = 0; f < 4; f++) accB1 = mfma_bf16(av[4 + f], as_bf16x8(wb[1][f]), accB1);
      LD_WH(1, 6);
      const float dtv = dt_s[t];
#pragma unroll
      for (int r = 0; r < 4; r++) {
        hreg[0][r] += dtv * (accB0[r] + bb2[0]);
        o_fr[wbase + r * 8] = (__bf16)hreg[0][r];
        hreg[1][r] += dtv * (accB1[r] + bb2[1]);
        o_fr[wbase + (r + 32) * 8] = (__bf16)hreg[1][r];
      }
    }
    BAR();

    // ---- Phase C: GRU gates; consume C0..C11 (bufs 2,3,4,5,6,0,1,2,3,4,5,6)
    f32x4 acc6[6], agi2[2];
#pragma unroll
    for (int q = 0; q < 6; q++) acc6[q] = (f32x4){0.f, 0.f, 0.f, 0.f};
    agi2[0] = (f32x4){0.f, 0.f, 0.f, 0.f};
    agi2[1] = (f32x4){0.f, 0.f, 0.f, 0.f};
    {
      bf16x8 ofv[4];
#pragma unroll
      for (int f = 0; f < 4; f++) ofv[f] = *(const bf16x8*)&o_fr[(f * 64 + l) * 8];
#pragma unroll
      for (int f = 0; f < 4; f++) acc6[0] = mfma_bf16(ofv[f], as_bf16x8(wb[2][f]), acc6[0]);
      LD_WH(2, 7);
#pragma unroll
      for (int f = 0; f < 4; f++) acc6[1] = mfma_bf16(ofv[f], as_bf16x8(wb[3][f]), acc6[1]);
      LD_WH(3, 8);
#pragma unroll
      for (int f = 0; f < 4; f++) acc6[2] = mfma_bf16(ofv[f], as_bf16x8(wb[4][f]), acc6[2]);
      LD_WH(4, 9);
#pragma unroll
      for (int f = 0; f < 4; f++) acc6[3] = mfma_bf16(ofv[f], as_bf16x8(wb[5][f]), acc6[3]);
      LD_WH(5, 10);
#pragma unroll
      for (int f = 0; f < 4; f++) acc6[4] = mfma_bf16(ofv[f], as_bf16x8(wb[6][f]), acc6[4]);
      LD_WH(6, 11);
#pragma unroll
      for (int f = 0; f < 4; f++) acc6[5] = mfma_bf16(ofv[f], as_bf16x8(wb[0][f]), acc6[5]);
      LD_X(0, t + 1);
      // hi kb-half
#pragma unroll
      for (int f = 0; f < 4; f++) ofv[f] = *(const bf16x8*)&o_fr[((4 + f) * 64 + l) * 8];
#pragma unroll
      for (int f = 0; f < 4; f++) acc6[0] = mfma_bf16(ofv[f], as_bf16x8(wb[1][f]), acc6[0]);
      LD_W1(1, 0);
#pragma unroll
      for (int f = 0; f < 4; f++) acc6[1] = mfma_bf16(ofv[f], as_bf16x8(wb[2][f]), acc6[1]);
      LD_W1(2, 1);
#pragma unroll
      for (int f = 0; f < 4; f++) acc6[2] = mfma_bf16(ofv[f], as_bf16x8(wb[3][f]), acc6[2]);
      LD_W1(3, 2);
#pragma unroll
      for (int f = 0; f < 4; f++) acc6[3] = mfma_bf16(ofv[f], as_bf16x8(wb[4][f]), acc6[3]);
      LD_W1(4, 3);
#pragma unroll
      for (int f = 0; f < 4; f++) acc6[4] = mfma_bf16(ofv[f], as_bf16x8(wb[5][f]), acc6[4]);
      LD_W2(5, 0);
#pragma unroll
      for (int f = 0; f < 4; f++) acc6[5] = mfma_bf16(ofv[f], as_bf16x8(wb[6][f]), acc6[5]);
      LD_W2(6, 1);
    }
    // wih contributions (LDS-resident)
#pragma unroll
    for (int gg = 0; gg < 3; gg++) {
#pragma unroll
      for (int f = 0; f < 4; f++) {
        const int tile = gg * 16 + 2 * wv + (f >> 1);
        bf16x8 wf = wifl[(tile * 2 + (f & 1)) * 64 + l];
        if (gg < 2)
          acc6[gg * 2 + (f >> 1)] = mfma_bf16((f & 1) ? xf1 : xf0, wf, acc6[gg * 2 + (f >> 1)]);
        else
          agi2[f >> 1] = mfma_bf16((f & 1) ? xf1 : xf0, wf, agi2[f >> 1]);
      }
    }

    // ---- nonlinearity + state update
#pragma unroll
    for (int nt = 0; nt < 2; nt++) {
#pragma unroll
      for (int r = 0; r < 4; r++) {
        float rg = fast_sigmoid(acc6[nt][r] + brz[nt]);
        float zg = fast_sigmoid(acc6[2 + nt][r] + brz[2 + nt]);
        float ng = fast_tanh(agi2[nt][r] + bin[nt] + rg * (acc6[4 + nt][r] + bhn[nt]));
        float hn = (1.f - zg) * ng + zg * hreg[nt][r];
        hreg[nt][r] = hn;
        if (t == len4[r] - 1) hlast[4 * g + r][32 * wv + 16 * nt + c] = hn;
        h_fr[wbase + (r + 32 * nt) * 8] = (__bf16)hn;
      }
    }
    BAR();
  }

  // ---- Output: out = h_last @ w_out^T + b_out (bf16 hi/lo split, ~fp32)
  const bf16x8* woh = (const bf16x8*)wouth;
  const bf16x8* wol = (const bf16x8*)woutl;
  f32x4 oa[2] = {{0.f, 0.f, 0.f, 0.f}, {0.f, 0.f, 0.f, 0.f}};
#pragma unroll
  for (int kb = 0; kb < 8; kb++) {
    f32x4 v0 = *(const f32x4*)&hlast[c][kb * 32 + 8 * g];
    f32x4 v1 = *(const f32x4*)&hlast[c][kb * 32 + 8 * g + 4];
    bf16x8 hhi, hlo;
#pragma unroll
    for (int j = 0; j < 4; j++) {
      __bf16 p = (__bf16)v0[j]; hhi[j] = p; hlo[j] = (__bf16)(v0[j] - (float)p);
      __bf16 q = (__bf16)v1[j]; hhi[4 + j] = q; hlo[4 + j] = (__bf16)(v1[j] - (float)q);
    }
#pragma unroll
    for (int nt = 0; nt < 2; nt++) {
      int tile = 2 * wv + nt;
      oa[nt] = mfma_bf16(hhi, woh[(tile * 8 + kb) * 64 + l], oa[nt]);
      oa[nt] = mfma_bf16(hlo, woh[(tile * 8 + kb) * 64 + l], oa[nt]);
      oa[nt] = mfma_bf16(hhi, wol[(tile * 8 + kb) * 64 + l], oa[nt]);
    }
  }
#pragma unroll
  for (int nt = 0; nt < 2; nt++)
#pragma unroll
    for (int r = 0; r < 4; r++)
      out[(size_t)(m0 + 4 * g + r) * Hn + 32 * wv + 16 * nt + c] = oa[nt][r] + bo[nt];
}

extern "C" void kernel_launch(void* const* d_in, const int* in_sizes, int n_in,
                              void* d_out, int out_size, void* d_ws, size_t ws_size,
                              hipStream_t stream) {
  const float* x = (const float*)d_in[0];
  const float* tps = (const float*)d_in[1];
  const float* mask = (const float*)d_in[2];
  const float* w_ih = (const float*)d_in[3];
  const float* w_hh = (const float*)d_in[4];
  const float* b_ih = (const float*)d_in[5];
  const float* b_hh = (const float*)d_in[6];
  const float* w1 = (const float*)d_in[7];
  const float* b1 = (const float*)d_in[8];
  const float* w2 = (const float*)d_in[9];
  const float* b2 = (const float*)d_in[10];
  const float* w_out = (const float*)d_in[11];
  const float* b_out = (const float*)d_in[12];

  char* ws = (char*)d_ws;
  __bf16* w1p = (__bf16*)(ws + 0);         // 131072 B
  __bf16* w2p = (__bf16*)(ws + 131072);    // 131072 B
  __bf16* whhp = (__bf16*)(ws + 262144);   // 393216 B
  __bf16* wihp = (__bf16*)(ws + 655360);   // 98304 B
  __bf16* wouth = (__bf16*)(ws + 753664);  // 131072 B
  __bf16* woutl = (__bf16*)(ws + 884736);  // 131072 B  (total < 1 MB)

  pack_w<<<(256 * 256 + 255) / 256, 256, 0, stream>>>(w1, w1p, 256, 256);
  pack_w<<<(256 * 256 + 255) / 256, 256, 0, stream>>>(w2, w2p, 256, 256);
  pack_w<<<(768 * 256 + 255) / 256, 256, 0, stream>>>(w_hh, whhp, 768, 256);
  pack_w<<<(768 * 64 + 255) / 256, 256, 0, stream>>>(w_ih, wihp, 768, 64);
  pack_w_hilo<<<(256 * 256 + 255) / 256, 256, 0, stream>>>(w_out, wouth, woutl, 256, 256);

  gru_ode_kernel<<<32, 512, 0, stream>>>(x, tps, mask, b_ih, b_hh, b1, b2, b_out,
                                         w1p, w2p, whhp, wihp, wouth, woutl,
                                         (float*)d_out);
}